// Round 10
// baseline (559.840 us; speedup 1.0000x reference)
//
#include <hip/hip_runtime.h>
#include <cstdint>
#include <cstddef>

// B=8, S=12, N=4096, F=4, H=64
// r19 = r18 base (549us; XCD remap was NULL -> dropped) with s1 retile:
//  - BM 128 -> 256 (BN=128, BK=128 kept): B-panel duplication 32x -> 16x
//    => staged traffic 128 -> 96 MB/dispatch (-25%). Theory: s1 is
//    L3-staging-BW-bound (~9.1 TB/s effective), so traffic is the only lever.
//  - 512 thr / 8 waves, per-wave 64x64 = r15's exact 4x4-frag structure;
//    wm in {0,64,128,192} (mult of 8) -> identical LDS swizzle formulas.
//    LDS 96KB -> 1 blk/CU, 8 waves/CU (same wave count as r15's 2x4).
//  - Grid H: dim3(16,4,4)=256 blocks; comb flat 448 (256 H + 192 X).
//  - s2 v3 / enc / dec(r17-fold) / setup unchanged.

typedef unsigned short u16;
typedef short s8v __attribute__((ext_vector_type(8)));     // 8 x bf16 bits
typedef unsigned short h8v __attribute__((ext_vector_type(8))); // 8 x u16
typedef float f4v __attribute__((ext_vector_type(4)));     // fp32 MFMA acc
typedef int   i4v __attribute__((ext_vector_type(4)));     // i8 MFMA operands/acc

__device__ __forceinline__ u16 f2bf(float x){
  union { float f; uint32_t u; } v; v.f = x;
  uint32_t r = v.u + 0x7FFFu + ((v.u >> 16) & 1u);   // RNE
  return (u16)(r >> 16);
}
__device__ __forceinline__ float bf2f(u16 x){
  union { uint32_t u; float f; } v; v.u = ((uint32_t)x) << 16; return v.f;
}
__device__ __forceinline__ float frcp(float x){ return __builtin_amdgcn_rcpf(x); }
__device__ __forceinline__ float fsig(float x){ return frcp(1.0f + __expf(-x)); }
__device__ __forceinline__ float ftanh(float x){ return 1.0f - 2.0f * frcp(1.0f + __expf(2.0f * x)); }
__device__ __forceinline__ int8_t f2i8(float x){
  int v = (int)rintf(x);
  v = v > 127 ? 127 : (v < -127 ? -127 : v);
  return (int8_t)v;
}

typedef const __attribute__((address_space(1))) unsigned int* gp_t;
typedef __attribute__((address_space(3))) unsigned int* lp_t;
__device__ __forceinline__ void glds16(const void* g, void* l){
  __builtin_amdgcn_global_load_lds((gp_t)g, (lp_t)l, 16, 0, 0);
}

// ---------------- Stage-1 INT8 core r19: 256x128 tile, BK=128, dbuf, 8 waves --
// LDS: As 2x32KB + Bs 2x16KB = 96KB. Staging swizzle: phys chunk (row, cp)
// holds global chunk cp ^ (row&7); read chunk q' = (sub*4 + (l>>4)) ^ (l&7)
// (row&7 == l&7 since wm, mt*16 are multiples of 8) -> 2-way (free).
__device__ __forceinline__ void s1_core(int8_t* As, int8_t* Bs,
    const int8_t* __restrict__ A, const int8_t* __restrict__ Bt,
    u16* __restrict__ Cs, int Ncols, int ksl, float cscale,
    int mb, int nb, int k0)
{
  const int t  = threadIdx.x;          // 0..511
  const int l  = t & 63;
  const int w  = t >> 6;               // 0..7
  const int wm = (w >> 1) * 64;        // 0,64,128,192
  const int wc = (w & 1) * 64;         // 0,64

  i4v acc[4][4];
  #pragma unroll
  for (int i = 0; i < 4; ++i)
    #pragma unroll
    for (int j = 0; j < 4; ++j) acc[i][j] = (i4v)0;

  const int srow = t >> 3;             // 0..63
  const int gsw  = ((t & 7) ^ (srow & 7)) * 16;   // (srow+64j)&7 == srow&7
  const int8_t* ab = A  + (size_t)(mb + srow) * 4096 + k0 + gsw;
  const int8_t* bb = Bt + (size_t)(nb + srow) * 4096 + k0 + gsw;

  const int rA = l & 15;
  const int lsw = l & 7;

  // prefetch tile 0 into buf 0: A rows srow+64j (j=0..3), B rows srow+64j (j=0..1)
  #pragma unroll
  for (int j = 0; j < 4; ++j)
    glds16(ab + (size_t)(64 * j) * 4096, As + j * 8192 + t * 16);
  #pragma unroll
  for (int j = 0; j < 2; ++j)
    glds16(bb + (size_t)(64 * j) * 4096, Bs + j * 8192 + t * 16);

  for (int kk = 0; kk < ksl; kk += 128) {
    const int cur = (kk >> 7) & 1;
    __syncthreads();   // buf[cur] ready; buf[cur^1] free
    if (kk + 128 < ksl) {
      const int nxt = cur ^ 1;
      #pragma unroll
      for (int j = 0; j < 4; ++j)
        glds16(ab + (size_t)(64 * j) * 4096 + kk + 128, As + nxt * 32768 + j * 8192 + t * 16);
      #pragma unroll
      for (int j = 0; j < 2; ++j)
        glds16(bb + (size_t)(64 * j) * 4096 + kk + 128, Bs + nxt * 16384 + j * 8192 + t * 16);
    }
    const int aofs = cur * 32768;
    const int bofs = cur * 16384;
    #pragma unroll
    for (int sub = 0; sub < 2; ++sub) {
      const int kpos = ((sub * 4 + (l >> 4)) ^ lsw) * 16;
      i4v af[4], bf[4];
      #pragma unroll
      for (int mt = 0; mt < 4; ++mt)
        af[mt] = *(const i4v*)&As[aofs + (wm + mt * 16 + rA) * 128 + kpos];
      #pragma unroll
      for (int nt = 0; nt < 4; ++nt)
        bf[nt] = *(const i4v*)&Bs[bofs + (wc + nt * 16 + rA) * 128 + kpos];
      #pragma unroll
      for (int mt = 0; mt < 4; ++mt)
        #pragma unroll
        for (int nt = 0; nt < 4; ++nt)
          acc[mt][nt] = __builtin_amdgcn_mfma_i32_16x16x64_i8(af[mt], bf[nt], acc[mt][nt], 0, 0, 0);
    }
  }

  const int colo = l & 15;
  const int rowo = (l >> 4) * 4;
  #pragma unroll
  for (int mt = 0; mt < 4; ++mt)
    #pragma unroll
    for (int nt = 0; nt < 4; ++nt)
      #pragma unroll
      for (int r = 0; r < 4; ++r) {
        int gr = mb + wm + mt * 16 + rowo + r;
        int gc = nb + wc + nt * 16 + colo;
        Cs[(size_t)gr * Ncols + gc] = f2bf((float)acc[mt][nt][r] * cscale);
      }
}

__global__ __launch_bounds__(512)
void gemm_s1_i8(const int8_t* __restrict__ A, const int8_t* __restrict__ Bt,
                u16* __restrict__ Cpart, int Ncols, int ksl, float cscale)
{
  __shared__ __align__(16) int8_t lds[98304];
  s1_core(lds, lds + 65536, A, Bt, Cpart + (size_t)blockIdx.z * 4096 * Ncols,
          Ncols, ksl, cscale, blockIdx.x * 256, blockIdx.y * 128,
          blockIdx.z * ksl);
}

// combined: bids 0..255 = H-part (16x4x4), 256..447 = X-part (16x3x4)
__global__ __launch_bounds__(512)
void gemm_s1_comb(const int8_t* __restrict__ A, const int8_t* __restrict__ Xp,
                  const int8_t* __restrict__ PB,
                  u16* __restrict__ CpX, u16* __restrict__ CpH,
                  int ksl, float cs)
{
  __shared__ __align__(16) int8_t lds[98304];
  const int bid = blockIdx.x;
  if (bid < 256) {
    const int bx = bid & 15, by = (bid >> 4) & 3, bz = bid >> 6;
    s1_core(lds, lds + 65536, A, PB, CpH + (size_t)bz * 4096 * 512,
            512, ksl, cs, bx * 256, by * 128, bz * ksl);
  } else {
    const int q = bid - 256;
    const int bx = q & 15, s = q >> 4;
    const int by = s % 3, bz = s / 3;
    s1_core(lds, lds + 65536, A, Xp, CpX + (size_t)bz * 4096 * 384,
            384, ksl, cs, bx * 256, by * 128, bz * ksl);
  }
}

// O[i] = sum_{z<4} P[z*SL + i]  (bf16)
__global__ __launch_bounds__(256)
void reduceN(const u16* __restrict__ P, u16* __restrict__ O, size_t SL)
{
  size_t i = ((size_t)blockIdx.x * 256 + threadIdx.x) * 8;
  if (i >= SL) return;
  float s[8] = {0,0,0,0,0,0,0,0};
  #pragma unroll
  for (int z = 0; z < 4; ++z) {
    uint4 v = *(const uint4*)(P + z * SL + i);
    uint32_t wd[4] = {v.x, v.y, v.z, v.w};
    #pragma unroll
    for (int q = 0; q < 4; ++q) {
      union { uint32_t u; float f; } lo, hi;
      lo.u = wd[q] << 16; hi.u = wd[q] & 0xFFFF0000u;
      s[2*q] += lo.f; s[2*q+1] += hi.f;
    }
  }
  uint4 o; uint32_t* ow = (uint32_t*)&o;
  #pragma unroll
  for (int q = 0; q < 4; ++q)
    ow[q] = (uint32_t)f2bf(s[2*q]) | ((uint32_t)f2bf(s[2*q+1]) << 16);
  *(uint4*)(O + i) = o;
}

// ---------- Stage-2 v3: As (4-slice AH sum | AX | pad) in LDS; B-frags from
// fragment-ordered WTf (global, L1/L2-hot). Permuted G store.
__global__ __launch_bounds__(256)
void gemm_s2(const u16* __restrict__ AH, const u16* __restrict__ AXb,
             const u16* __restrict__ WTf, const float* __restrict__ b1v,
             const float* __restrict__ b2v, u16* __restrict__ G, int tstep)
{
  __shared__ u16 As[64 * 104];
  const int t = threadIdx.x;
  const int l = t & 63, w = t >> 6;
  const int wm = (w >> 1) * 32, wc0 = (w & 1) * 32;
  const int mb = blockIdx.x * 64;
  const size_t SL = 32768ull * 64;

  #pragma unroll
  for (int pass = 0; pass < 2; ++pass) {
    int idx = t + pass * 256;
    int row = idx >> 3, oct = idx & 7;
    size_t base = (size_t)(mb + row) * 64 + oct * 8;
    float s[8] = {0,0,0,0,0,0,0,0};
    #pragma unroll
    for (int z = 0; z < 4; ++z) {
      uint4 v = *(const uint4*)(AH + z * SL + base);
      uint32_t wd[4] = {v.x, v.y, v.z, v.w};
      #pragma unroll
      for (int q = 0; q < 4; ++q) {
        union { uint32_t u; float f; } lo, hi;
        lo.u = wd[q] << 16; hi.u = wd[q] & 0xFFFF0000u;
        s[2*q] += lo.f; s[2*q+1] += hi.f;
      }
    }
    uint4 o; uint32_t* ow = (uint32_t*)&o;
    #pragma unroll
    for (int q = 0; q < 4; ++q)
      ow[q] = (uint32_t)f2bf(s[2*q]) | ((uint32_t)f2bf(s[2*q+1]) << 16);
    *(uint4*)&As[row * 104 + oct * 8] = o;
  }
  {
    int row = t >> 2, q = t & 3;
    uint4 o = {0, 0, 0, 0};
    if (q == 0) {
      int r = mb + row, n = r >> 3, b = r & 7;
      const uint32_t* src = (const uint32_t*)(AXb + (size_t)n * 384 + tstep * 32 + b * 4);
      o.x = src[0]; o.y = src[1];
    }
    *(uint4*)&As[row * 104 + 64 + q * 8] = o;
  }
  __syncthreads();

  const int rA = l & 15, kg = (l >> 4) * 8;
  s8v af[3][2];
  #pragma unroll
  for (int kc = 0; kc < 3; ++kc)
    #pragma unroll
    for (int mt = 0; mt < 2; ++mt)
      af[kc][mt] = *(const s8v*)&As[(wm + mt * 16 + rA) * 104 + kc * 32 + kg];

  const int lchunk = ((l & 15) * 4 + (l >> 4)) * 8;   // lane offset in frag (u16)
  const int colo = l & 15, rowo = (l >> 4) * 4;
  #pragma unroll
  for (int nb4 = 0; nb4 < 4; ++nb4) {
    const int wc = nb4 * 64 + wc0;
    f4v acc[2][2];
    #pragma unroll
    for (int i = 0; i < 2; ++i)
      #pragma unroll
      for (int j = 0; j < 2; ++j) acc[i][j] = (f4v)0.0f;
    #pragma unroll
    for (int kc = 0; kc < 3; ++kc) {
      s8v bf[2];
      #pragma unroll
      for (int nt = 0; nt < 2; ++nt) {
        int ct = nb4 * 4 + (w & 1) * 2 + nt;
        bf[nt] = *(const s8v*)&WTf[(ct * 3 + kc) * 512 + lchunk];
      }
      #pragma unroll
      for (int mt = 0; mt < 2; ++mt)
        #pragma unroll
        for (int nt = 0; nt < 2; ++nt)
          acc[mt][nt] = __builtin_amdgcn_mfma_f32_16x16x32_bf16(af[kc][mt], bf[nt], acc[mt][nt], 0, 0, 0);
    }
    #pragma unroll
    for (int mt = 0; mt < 2; ++mt)
      #pragma unroll
      for (int nt = 0; nt < 2; ++nt) {
        int gc = wc + nt * 16 + colo;
        float bb = (gc < 192) ? b1v[gc] : b2v[gc - 192];
        #pragma unroll
        for (int r = 0; r < 4; ++r) {
          int gr = mb + wm + mt * 16 + rowo + r;
          int np = gr >> 3, b = gr & 7;
          float v = acc[mt][nt][r] + bb;
          size_t addr;
          u16 val;
          if (gc < 192) {
            int p = np * 192 + gc;
            int role = p >> 18;
            int k = p & 262143;
            addr = ((size_t)(role * 8 + b) << 18) + k;
            val = f2bf(fsig(v));
          } else {
            int k = np * 64 + (gc - 192);
            addr = ((size_t)(24 + b) << 18) + k;
            val = f2bf(ftanh(v));
          }
          G[addr] = val;
        }
      }
  }
}

// enc_update (t = 0..10 only): h update + PB repack.
__global__ __launch_bounds__(256)
void enc_update(const u16* __restrict__ G, const float* __restrict__ struc,
                int8_t* __restrict__ PB)
{
  __shared__ uint8_t hx[64 * 40];
  const int t = threadIdx.x;
  const int b = blockIdx.x >> 7;
  const int n0 = (blockIdx.x & 127) * 32;
  const int k8 = n0 * 64 + t * 8;
  const int nloc = t >> 3;
  const int hh0 = (t & 7) * 8;

  h8v f8 = *(const h8v*)&G[((size_t)(     b) << 18) + k8];
  h8v i8_ = *(const h8v*)&G[((size_t)( 8 + b) << 18) + k8];
  h8v o8 = *(const h8v*)&G[((size_t)(16 + b) << 18) + k8];
  h8v c8 = *(const h8v*)&G[((size_t)(24 + b) << 18) + k8];
  float4 s0 = *(const float4*)&struc[k8];
  float4 s1 = *(const float4*)&struc[k8 + 4];
  float sv[8] = {s0.x, s0.y, s0.z, s0.w, s1.x, s1.y, s1.z, s1.w};

  #pragma unroll
  for (int j = 0; j < 8; ++j) {
    float c = bf2f(f8[j]) * sv[j] + bf2f(i8_[j]) * bf2f(c8[j]);
    float hv = bf2f(o8[j]) * ftanh(c);
    hx[(hh0 + j) * 40 + nloc] = (uint8_t)f2i8(hv * 127.0f);
  }
  __syncthreads();
  {
    int row = t >> 2, seg = t & 3;
    uint2 v = *(const uint2*)&hx[row * 40 + seg * 8];
    *(uint2*)&PB[(size_t)(b * 64 + row) * 4096 + n0 + seg * 8] = v;
  }
}

// ---------------- Merged setup (r15) ----------------
__global__ __launch_bounds__(256)
void setup_all(const float* __restrict__ adj, int8_t* __restrict__ adj_i8,
               const float* __restrict__ W1, const float* __restrict__ W2,
               const float* __restrict__ Wih, const float* __restrict__ Whh,
               const float* __restrict__ D1,
               u16* __restrict__ WTf, u16* __restrict__ WihB,
               u16* __restrict__ WhhB, u16* __restrict__ D1t,
               const float* __restrict__ struc, int8_t* __restrict__ PB,
               const float* __restrict__ X, int8_t* __restrict__ Xp)
{
  const int blk = blockIdx.x;
  const int t = threadIdx.x;
  if (blk < 16384) {                         // conv_adj_i8
    size_t i = ((size_t)blk * 256 + t) * 4;
    float4 v = *(const float4*)(adj + i);
    const float s = 127.0f * 2048.0f;
    char4 o;
    o.x = f2i8(v.x * s); o.y = f2i8(v.y * s); o.z = f2i8(v.z * s); o.w = f2i8(v.w * s);
    *(char4*)(adj_i8 + i) = o;
  } else if (blk < 16616) {                  // build_w
    int gid = (blk - 16384) * 256 + t;
    if (gid < 24576) {
      int f = gid >> 9;          // frag 0..47
      int q = gid & 511;
      int ct = f / 3, kc = f - ct * 3;
      int c = q >> 3, e = q & 7;
      int rA = c >> 2, g = c & 3;
      int row = ct * 16 + rA;            // gate col 0..255
      int ch = kc * 32 + g * 8 + e;      // k index 0..95
      float v = 0.0f;
      int rr = (ch < 64) ? (ch + 4) : (ch < 68 ? ch - 64 : -1);
      if (rr >= 0) v = (row < 192) ? W1[(size_t)rr * 192 + row] : W2[(size_t)rr * 64 + (row - 192)];
      WTf[gid] = f2bf(v);
    } else if (gid < 40960) {
      int q = gid - 24576; WihB[q] = f2bf(Wih[q]);
    } else if (gid < 57344) {
      int q = gid - 40960; WhhB[q] = f2bf(Whh[q]);
    } else if (gid < 59392) {
      int q = gid - 57344;
      int j = q >> 6, hh = q & 63;
      D1t[q] = f2bf(D1[(size_t)hh * 32 + j]);
    }
  } else if (blk < 24808) {                  // init_pb
    int gid = (blk - 16616) * 256 + t;
    int n = gid & 4095;
    int r = gid >> 12;
    int hh = r & 63;
    PB[(size_t)r * 4096 + n] = f2i8(struc[(size_t)n * 64 + hh] * 25.4f);
  } else {                                   // pack_xall
    int gid = (blk - 24808) * 256 + t;
    int n = gid & 4095;
    int col = gid >> 12;
    int ts = col >> 5, r = col & 31, b = r >> 2, f = r & 3;
    Xp[(size_t)col * 4096 + n] = f2i8(X[(((size_t)(b * 12 + ts)) * 4096 + n) * 4 + f] * 25.4f);
  }
}

// ---------------- Fused decoder r17: enc(11) folded into prologue ------------
#define DSTR 80
__global__ __launch_bounds__(512, 4)
void dec_fused(const u16* __restrict__ G, const float* __restrict__ struc,
               float* __restrict__ zout,
               const u16* __restrict__ WihB, const u16* __restrict__ WhhB,
               const float* __restrict__ bih, const float* __restrict__ bhh,
               const u16* __restrict__ D1t, const float* __restrict__ bd1,
               const float* __restrict__ D2, const float* __restrict__ bd2,
               float* __restrict__ recon)
{
  __shared__ u16 whl[256 * DSTR];
  __shared__ u16 hl[64 * DSTR];
  __shared__ u16 zl[64 * DSTR];
  const int t = threadIdx.x;
  const int l = t & 63;
  const int w = t >> 6;          // 0..7
  const int wg = w >> 1;         // row group 0..3
  const int half = w & 1;        // gate-col half
  const int r0 = blockIdx.x * 64;
  const int rA = l & 15;
  const int kg = (l >> 4) * 8;

  // stage Whh
  for (int c = t; c < 2048; c += 512) {
    int j = c >> 3, k8 = (c & 7) * 8;
    *(uint4*)&whl[j * DSTR + k8] = *(const uint4*)&WhhB[j * 64 + k8];
  }

  // ---- enc(11) fold: compute z for this block's 64 rows from G ----
  {
    const int b = r0 >> 12;
    const size_t base = (size_t)(r0 & 4095) * 64 + t * 8;   // n*64+hh flat
    h8v f8 = *(const h8v*)&G[((size_t)(     b) << 18) + base];
    h8v i8_ = *(const h8v*)&G[((size_t)( 8 + b) << 18) + base];
    h8v o8 = *(const h8v*)&G[((size_t)(16 + b) << 18) + base];
    h8v c8 = *(const h8v*)&G[((size_t)(24 + b) << 18) + base];
    float4 s0 = *(const float4*)&struc[base];
    float4 s1 = *(const float4*)&struc[base + 4];
    float sv[8] = {s0.x, s0.y, s0.z, s0.w, s1.x, s1.y, s1.z, s1.w};
    float hv[8];
    #pragma unroll
    for (int j = 0; j < 8; ++j) {
      float c = bf2f(f8[j]) * sv[j] + bf2f(i8_[j]) * bf2f(c8[j]);
      hv[j] = bf2f(o8[j]) * ftanh(c);
    }
    float4 z0 = {hv[0], hv[1], hv[2], hv[3]};
    float4 z1 = {hv[4], hv[5], hv[6], hv[7]};
    *(float4*)&zout[((size_t)b << 18) + base] = z0;
    *(float4*)&zout[((size_t)b << 18) + base + 4] = z1;
    h8v zb;
    #pragma unroll
    for (int j = 0; j < 8; ++j) zb[j] = f2bf(hv[j]);
    *(h8v*)&zl[(t >> 3) * DSTR + (t & 7) * 8] = zb;
  }
  __syncthreads();   // zl + whl ready

  f4v xg[8];
  {
    s8v a0 = *(const s8v*)&zl[(wg * 16 + rA) * DSTR + kg];
    s8v a1 = *(const s8v*)&zl[(wg * 16 + rA) * DSTR + 32 + kg];
    #pragma unroll
    for (int j = 0; j < 8; ++j) {
      int nt = (j >> 1) * 4 + half * 2 + (j & 1);
      s8v b0 = *(const s8v*)&WihB[(nt * 16 + rA) * 64 + kg];
      s8v b1 = *(const s8v*)&WihB[(nt * 16 + rA) * 64 + 32 + kg];
      f4v a = (f4v)0.0f;
      a = __builtin_amdgcn_mfma_f32_16x16x32_bf16(a0, b0, a, 0, 0, 0);
      a = __builtin_amdgcn_mfma_f32_16x16x32_bf16(a1, b1, a, 0, 0, 0);
      float bb = bih[nt * 16 + rA] + bhh[nt * 16 + rA];
      #pragma unroll
      for (int r = 0; r < 4; ++r) xg[j][r] = a[r] + bb;
    }
  }
  s8v d1f[4];
  #pragma unroll
  for (int nt2 = 0; nt2 < 2; ++nt2)
    #pragma unroll
    for (int kc = 0; kc < 2; ++kc)
      d1f[nt2 * 2 + kc] = *(const s8v*)&D1t[(nt2 * 16 + rA) * 64 + kc * 32 + kg];
  const float bd1x = bd1[rA], bd1y = bd1[16 + rA];
  const float d2x = D2[rA], d2y = D2[16 + rA];
  const float bd2v = bd2[0];

  float cst[8];
  #pragma unroll
  for (int q = 0; q < 8; ++q) cst[q] = 0.0f;
  s8v ha0 = (s8v)0, ha1 = (s8v)0;

  for (int s = 0; s < 12; ++s) {
    f4v acc[8];
    #pragma unroll
    for (int j = 0; j < 8; ++j) acc[j] = xg[j];
    if (s > 0) {
      #pragma unroll
      for (int j = 0; j < 8; ++j) {
        int nt = (j >> 1) * 4 + half * 2 + (j & 1);
        s8v b0 = *(const s8v*)&whl[(nt * 16 + rA) * DSTR + kg];
        s8v b1 = *(const s8v*)&whl[(nt * 16 + rA) * DSTR + 32 + kg];
        acc[j] = __builtin_amdgcn_mfma_f32_16x16x32_bf16(ha0, b0, acc[j], 0, 0, 0);
        acc[j] = __builtin_amdgcn_mfma_f32_16x16x32_bf16(ha1, b1, acc[j], 0, 0, 0);
      }
    }
    __syncthreads();
    #pragma unroll
    for (int ql = 0; ql < 2; ++ql) {
      int q = half * 2 + ql;
      #pragma unroll
      for (int r = 0; r < 4; ++r) {
        float i_ = fsig (acc[0 + ql][r]);
        float f_ = fsig (acc[2 + ql][r]);
        float g_ = ftanh(acc[4 + ql][r]);
        float o_ = fsig (acc[6 + ql][r]);
        float cc = f_ * cst[ql * 4 + r] + i_ * g_;
        cst[ql * 4 + r] = cc;
        float hv = o_ * ftanh(cc);
        hl[(wg * 16 + (l >> 4) * 4 + r) * DSTR + q * 16 + rA] = f2bf(hv);
      }
    }
    __syncthreads();
    ha0 = *(const s8v*)&hl[(wg * 16 + rA) * DSTR + kg];
    ha1 = *(const s8v*)&hl[(wg * 16 + rA) * DSTR + 32 + kg];
    if (half == 0) {
      f4v m0 = (f4v)0.0f, m1 = (f4v)0.0f;
      m0 = __builtin_amdgcn_mfma_f32_16x16x32_bf16(ha0, d1f[0], m0, 0, 0, 0);
      m0 = __builtin_amdgcn_mfma_f32_16x16x32_bf16(ha1, d1f[1], m0, 0, 0, 0);
      m1 = __builtin_amdgcn_mfma_f32_16x16x32_bf16(ha0, d1f[2], m1, 0, 0, 0);
      m1 = __builtin_amdgcn_mfma_f32_16x16x32_bf16(ha1, d1f[3], m1, 0, 0, 0);
      f4v p;
      #pragma unroll
      for (int r = 0; r < 4; ++r)
        p[r] = fmaxf(m0[r] + bd1x, 0.0f) * d2x + fmaxf(m1[r] + bd1y, 0.0f) * d2y;
      #pragma unroll
      for (int mask = 1; mask < 16; mask <<= 1)
        #pragma unroll
        for (int r = 0; r < 4; ++r) p[r] += __shfl_xor(p[r], mask);
      if (rA < 4)
        recon[(size_t)(r0 + wg * 16 + (l >> 4) * 4 + rA) * 12 + s] = p[rA] + bd2v;
    }
  }
}

extern "C" void kernel_launch(void* const* d_in, const int* in_sizes, int n_in,
                              void* d_out, int out_size, void* d_ws, size_t ws_size,
                              hipStream_t stream)
{
  (void)in_sizes; (void)n_in; (void)out_size; (void)ws_size;
  const float* X     = (const float*)d_in[0];
  const float* adj   = (const float*)d_in[1];
  const float* struc = (const float*)d_in[2];
  const float* W1    = (const float*)d_in[3];
  const float* b1    = (const float*)d_in[4];
  const float* W2    = (const float*)d_in[5];
  const float* b2    = (const float*)d_in[6];
  const float* Wih   = (const float*)d_in[7];
  const float* Whh   = (const float*)d_in[8];
  const float* bih   = (const float*)d_in[9];
  const float* bhh   = (const float*)d_in[10];
  const float* D1    = (const float*)d_in[11];
  const float* bd1   = (const float*)d_in[12];
  const float* D2    = (const float*)d_in[13];
  const float* bd2   = (const float*)d_in[14];

  char* ws = (char*)d_ws;
  size_t off = 0;
  auto alloc = [&](size_t bytes){ void* p = ws + off; off += (bytes + 255) & ~(size_t)255; return p; };
  int8_t* adj_i8 = (int8_t*)alloc(4096ull * 4096);       // 16.75 MB
  int8_t* PB     = (int8_t*)alloc(512ull * 4096);        // h cols i8 [b*64+hh][n]
  int8_t* Xp     = (int8_t*)alloc(384ull * 4096);        // x cols i8 (scale 25.4)
  u16*   AXb    = (u16*)  alloc(4096ull * 384 * 2);      // adj@X bf16, all steps
  u16*   Cpart  = (u16*)  alloc(4ull * 4096 * 512 * 2);  // split-K slices (H)
  u16*   CpartX = (u16*)  alloc(4ull * 4096 * 384 * 2);  // split-K slices (X)
  u16*   G      = (u16*)  alloc(4ull * 8 * 262144 * 2);  // permuted gates
  u16*   WTf    = (u16*)  alloc(256ull * 96 * 2);        // fragment-ordered weights
  u16*   WihB   = (u16*)  alloc(256ull * 64 * 2);
  u16*   WhhB   = (u16*)  alloc(256ull * 64 * 2);
  u16*   D1t    = (u16*)  alloc(32ull * 64 * 2);

  float* zout  = (float*)d_out;                   // [B,N,H]
  float* recon = (float*)d_out + 2097152;         // [B*N, S] flat

  // dequant scales: adj lsb = 1/(127*2048); struc/X lsb = 1/25.4; h lsb = 1/127
  const float cs5 = (float)(2.0 / 4096.0 * 5.0 / (127.0 * 127.0));  // adj x (struc/X)
  const float cs1 = (float)(2.0 / 4096.0 * 1.0 / (127.0 * 127.0));  // adj x h

  setup_all<<<30952, 256, 0, stream>>>(adj, adj_i8, W1, W2, Wih, Whh, D1,
                                       WTf, WihB, WhhB, D1t, struc, PB, X, Xp);
  // combined: first adj@PB (bids 0..255) + adj@X (bids 256..447)
  gemm_s1_comb<<<448, 512, 0, stream>>>(adj_i8, Xp, PB, CpartX, Cpart, 1024, cs5);
  reduceN<<<768, 256, 0, stream>>>(CpartX, AXb, 4096ull * 384);

  for (int t = 0; t < 12; ++t) {
    if (t > 0)
      gemm_s1_i8<<<dim3(16, 4, 4), 512, 0, stream>>>(adj_i8, PB, Cpart, 512, 1024, cs1);
    gemm_s2<<<512, 256, 0, stream>>>(Cpart, AXb, WTf, b1, b2, G, t);
    if (t < 11)
      enc_update<<<1024, 256, 0, stream>>>(G, struc, PB);
  }

  dec_fused<<<512, 512, 0, stream>>>(G, struc, zout, WihB, WhhB, bih, bhh,
                                     D1t, bd1, D2, bd2, recon);
}

// Round 11
// 550.199 us; speedup vs baseline: 1.0175x; 1.0175x over previous
//
#include <hip/hip_runtime.h>
#include <cstdint>
#include <cstddef>

// B=8, S=12, N=4096, F=4, H=64
// r20 = r17/r18 config restored (549us; r19's BM=256 retile REVERTED — s1
// ledger: occupancy up hurt, locality null, traffic down hurt => r15 128x128
// BK=128 2-blk/CU structure is the local optimum at ~62% of i8 ceiling) with:
//  - reduceN FOLDED into gemm_s2's x-col staging: f2bf(sum_z CpartX slices)
//    computed in place — bit-identical to the old AXb path. Deletes one
//    dispatch + boundary + the 3MB AXb round-trip. AXb buffer removed.

typedef unsigned short u16;
typedef short s8v __attribute__((ext_vector_type(8)));     // 8 x bf16 bits
typedef unsigned short h8v __attribute__((ext_vector_type(8))); // 8 x u16
typedef float f4v __attribute__((ext_vector_type(4)));     // fp32 MFMA acc
typedef int   i4v __attribute__((ext_vector_type(4)));     // i8 MFMA operands/acc

__device__ __forceinline__ u16 f2bf(float x){
  union { float f; uint32_t u; } v; v.f = x;
  uint32_t r = v.u + 0x7FFFu + ((v.u >> 16) & 1u);   // RNE
  return (u16)(r >> 16);
}
__device__ __forceinline__ float bf2f(u16 x){
  union { uint32_t u; float f; } v; v.u = ((uint32_t)x) << 16; return v.f;
}
__device__ __forceinline__ float frcp(float x){ return __builtin_amdgcn_rcpf(x); }
__device__ __forceinline__ float fsig(float x){ return frcp(1.0f + __expf(-x)); }
__device__ __forceinline__ float ftanh(float x){ return 1.0f - 2.0f * frcp(1.0f + __expf(2.0f * x)); }
__device__ __forceinline__ int8_t f2i8(float x){
  int v = (int)rintf(x);
  v = v > 127 ? 127 : (v < -127 ? -127 : v);
  return (int8_t)v;
}

typedef const __attribute__((address_space(1))) unsigned int* gp_t;
typedef __attribute__((address_space(3))) unsigned int* lp_t;
__device__ __forceinline__ void glds16(const void* g, void* l){
  __builtin_amdgcn_global_load_lds((gp_t)g, (lp_t)l, 16, 0, 0);
}

// ---------------- Stage-1 INT8 core (r15): 128x128 tile, BK=128, dbuf --------
__device__ __forceinline__ void s1_core(int8_t* As, int8_t* Bs,
    const int8_t* __restrict__ A, const int8_t* __restrict__ Bt,
    u16* __restrict__ Cs, int Ncols, int ksl, float cscale,
    int mb, int nb, int k0)
{
  const int t  = threadIdx.x;
  const int l  = t & 63;
  const int w  = t >> 6;
  const int wm = (w >> 1) * 64;
  const int wc = (w & 1) * 64;

  i4v acc[4][4];
  #pragma unroll
  for (int i = 0; i < 4; ++i)
    #pragma unroll
    for (int j = 0; j < 4; ++j) acc[i][j] = (i4v)0;

  const int srow = t >> 3;
  const int gsw  = ((t & 7) ^ (srow & 7)) * 16;
  const int8_t* ab = A  + (size_t)(mb + srow) * 4096 + k0 + gsw;
  const int8_t* bb = Bt + (size_t)(nb + srow) * 4096 + k0 + gsw;

  const int rA = l & 15;
  const int lsw = l & 7;

  #pragma unroll
  for (int j = 0; j < 4; ++j) {
    glds16(ab + (size_t)(32 * j) * 4096, As + j * 4096 + t * 16);
    glds16(bb + (size_t)(32 * j) * 4096, Bs + j * 4096 + t * 16);
  }

  for (int kk = 0; kk < ksl; kk += 128) {
    const int cur = (kk >> 7) & 1;
    __syncthreads();
    if (kk + 128 < ksl) {
      const int nxt = cur ^ 1;
      #pragma unroll
      for (int j = 0; j < 4; ++j) {
        glds16(ab + (size_t)(32 * j) * 4096 + kk + 128, As + nxt * 16384 + j * 4096 + t * 16);
        glds16(bb + (size_t)(32 * j) * 4096 + kk + 128, Bs + nxt * 16384 + j * 4096 + t * 16);
      }
    }
    const int bofs = cur * 16384;
    #pragma unroll
    for (int sub = 0; sub < 2; ++sub) {
      const int kpos = ((sub * 4 + (l >> 4)) ^ lsw) * 16;
      i4v af[4], bf[4];
      #pragma unroll
      for (int mt = 0; mt < 4; ++mt)
        af[mt] = *(const i4v*)&As[bofs + (wm + mt * 16 + rA) * 128 + kpos];
      #pragma unroll
      for (int nt = 0; nt < 4; ++nt)
        bf[nt] = *(const i4v*)&Bs[bofs + (wc + nt * 16 + rA) * 128 + kpos];
      #pragma unroll
      for (int mt = 0; mt < 4; ++mt)
        #pragma unroll
        for (int nt = 0; nt < 4; ++nt)
          acc[mt][nt] = __builtin_amdgcn_mfma_i32_16x16x64_i8(af[mt], bf[nt], acc[mt][nt], 0, 0, 0);
    }
  }

  const int colo = l & 15;
  const int rowo = (l >> 4) * 4;
  #pragma unroll
  for (int mt = 0; mt < 4; ++mt)
    #pragma unroll
    for (int nt = 0; nt < 4; ++nt)
      #pragma unroll
      for (int r = 0; r < 4; ++r) {
        int gr = mb + wm + mt * 16 + rowo + r;
        int gc = nb + wc + nt * 16 + colo;
        Cs[(size_t)gr * Ncols + gc] = f2bf((float)acc[mt][nt][r] * cscale);
      }
}

__global__ __launch_bounds__(256)
void gemm_s1_i8(const int8_t* __restrict__ A, const int8_t* __restrict__ Bt,
                u16* __restrict__ Cpart, int Ncols, int ksl, float cscale)
{
  __shared__ int8_t As[2 * 128 * 128];
  __shared__ int8_t Bs[2 * 128 * 128];
  s1_core(As, Bs, A, Bt, Cpart + (size_t)blockIdx.z * 4096 * Ncols,
          Ncols, ksl, cscale, blockIdx.x * 128, blockIdx.y * 128,
          blockIdx.z * ksl);
}

// combined: by<3 -> X-part (Ncols 384), by>=3 -> PB-part (Ncols 512)
__global__ __launch_bounds__(256)
void gemm_s1_comb(const int8_t* __restrict__ A, const int8_t* __restrict__ Xp,
                  const int8_t* __restrict__ PB,
                  u16* __restrict__ CpX, u16* __restrict__ CpH,
                  int ksl, float cs)
{
  __shared__ int8_t As[2 * 128 * 128];
  __shared__ int8_t Bs[2 * 128 * 128];
  const int by = blockIdx.y;
  if (by < 3)
    s1_core(As, Bs, A, Xp, CpX + (size_t)blockIdx.z * 4096 * 384,
            384, ksl, cs, blockIdx.x * 128, by * 128, blockIdx.z * ksl);
  else
    s1_core(As, Bs, A, PB, CpH + (size_t)blockIdx.z * 4096 * 512,
            512, ksl, cs, blockIdx.x * 128, (by - 3) * 128, blockIdx.z * ksl);
}

// ---------- Stage-2 v4: As (4-slice AH sum | folded AX reduction | pad) in
// LDS; B-frags from fragment-ordered WTf (global, L1/L2-hot). Permuted G store.
__global__ __launch_bounds__(256)
void gemm_s2(const u16* __restrict__ AH, const u16* __restrict__ CpX,
             const u16* __restrict__ WTf, const float* __restrict__ b1v,
             const float* __restrict__ b2v, u16* __restrict__ G, int tstep)
{
  __shared__ u16 As[64 * 104];
  const int t = threadIdx.x;
  const int l = t & 63, w = t >> 6;
  const int wm = (w >> 1) * 32, wc0 = (w & 1) * 32;
  const int mb = blockIdx.x * 64;
  const size_t SL = 32768ull * 64;
  const size_t SLX = 4096ull * 384;

  #pragma unroll
  for (int pass = 0; pass < 2; ++pass) {
    int idx = t + pass * 256;
    int row = idx >> 3, oct = idx & 7;
    size_t base = (size_t)(mb + row) * 64 + oct * 8;
    float s[8] = {0,0,0,0,0,0,0,0};
    #pragma unroll
    for (int z = 0; z < 4; ++z) {
      uint4 v = *(const uint4*)(AH + z * SL + base);
      uint32_t wd[4] = {v.x, v.y, v.z, v.w};
      #pragma unroll
      for (int q = 0; q < 4; ++q) {
        union { uint32_t u; float f; } lo, hi;
        lo.u = wd[q] << 16; hi.u = wd[q] & 0xFFFF0000u;
        s[2*q] += lo.f; s[2*q+1] += hi.f;
      }
    }
    uint4 o; uint32_t* ow = (uint32_t*)&o;
    #pragma unroll
    for (int q = 0; q < 4; ++q)
      ow[q] = (uint32_t)f2bf(s[2*q]) | ((uint32_t)f2bf(s[2*q+1]) << 16);
    *(uint4*)&As[row * 104 + oct * 8] = o;
  }
  // x-cols (k 64..95): folded reduceN — sum 4 CpartX slices, f2bf in place.
  // Bit-identical to the old AXb path (same fp32-sum -> f2bf).
  {
    int row = t >> 2, q = t & 3;
    uint4 o = {0, 0, 0, 0};
    if (q == 0) {
      int r = mb + row, n = r >> 3, b = r & 7;
      size_t base = (size_t)n * 384 + tstep * 32 + b * 4;
      float s[4] = {0, 0, 0, 0};
      #pragma unroll
      for (int z = 0; z < 4; ++z) {
        uint2 v = *(const uint2*)(CpX + z * SLX + base);
        uint32_t wd[2] = {v.x, v.y};
        #pragma unroll
        for (int qq = 0; qq < 2; ++qq) {
          union { uint32_t u; float f; } lo, hi;
          lo.u = wd[qq] << 16; hi.u = wd[qq] & 0xFFFF0000u;
          s[2*qq] += lo.f; s[2*qq+1] += hi.f;
        }
      }
      uint32_t* ow = (uint32_t*)&o;
      ow[0] = (uint32_t)f2bf(s[0]) | ((uint32_t)f2bf(s[1]) << 16);
      ow[1] = (uint32_t)f2bf(s[2]) | ((uint32_t)f2bf(s[3]) << 16);
    }
    *(uint4*)&As[row * 104 + 64 + q * 8] = o;
  }
  __syncthreads();

  const int rA = l & 15, kg = (l >> 4) * 8;
  s8v af[3][2];
  #pragma unroll
  for (int kc = 0; kc < 3; ++kc)
    #pragma unroll
    for (int mt = 0; mt < 2; ++mt)
      af[kc][mt] = *(const s8v*)&As[(wm + mt * 16 + rA) * 104 + kc * 32 + kg];

  const int lchunk = ((l & 15) * 4 + (l >> 4)) * 8;   // lane offset in frag (u16)
  const int colo = l & 15, rowo = (l >> 4) * 4;
  #pragma unroll
  for (int nb4 = 0; nb4 < 4; ++nb4) {
    const int wc = nb4 * 64 + wc0;
    f4v acc[2][2];
    #pragma unroll
    for (int i = 0; i < 2; ++i)
      #pragma unroll
      for (int j = 0; j < 2; ++j) acc[i][j] = (f4v)0.0f;
    #pragma unroll
    for (int kc = 0; kc < 3; ++kc) {
      s8v bf[2];
      #pragma unroll
      for (int nt = 0; nt < 2; ++nt) {
        int ct = nb4 * 4 + (w & 1) * 2 + nt;
        bf[nt] = *(const s8v*)&WTf[(ct * 3 + kc) * 512 + lchunk];
      }
      #pragma unroll
      for (int mt = 0; mt < 2; ++mt)
        #pragma unroll
        for (int nt = 0; nt < 2; ++nt)
          acc[mt][nt] = __builtin_amdgcn_mfma_f32_16x16x32_bf16(af[kc][mt], bf[nt], acc[mt][nt], 0, 0, 0);
    }
    #pragma unroll
    for (int mt = 0; mt < 2; ++mt)
      #pragma unroll
      for (int nt = 0; nt < 2; ++nt) {
        int gc = wc + nt * 16 + colo;
        float bb = (gc < 192) ? b1v[gc] : b2v[gc - 192];
        #pragma unroll
        for (int r = 0; r < 4; ++r) {
          int gr = mb + wm + mt * 16 + rowo + r;
          int np = gr >> 3, b = gr & 7;
          float v = acc[mt][nt][r] + bb;
          size_t addr;
          u16 val;
          if (gc < 192) {
            int p = np * 192 + gc;
            int role = p >> 18;
            int k = p & 262143;
            addr = ((size_t)(role * 8 + b) << 18) + k;
            val = f2bf(fsig(v));
          } else {
            int k = np * 64 + (gc - 192);
            addr = ((size_t)(24 + b) << 18) + k;
            val = f2bf(ftanh(v));
          }
          G[addr] = val;
        }
      }
  }
}

// enc_update (t = 0..10 only): h update + PB repack.
__global__ __launch_bounds__(256)
void enc_update(const u16* __restrict__ G, const float* __restrict__ struc,
                int8_t* __restrict__ PB)
{
  __shared__ uint8_t hx[64 * 40];
  const int t = threadIdx.x;
  const int b = blockIdx.x >> 7;
  const int n0 = (blockIdx.x & 127) * 32;
  const int k8 = n0 * 64 + t * 8;
  const int nloc = t >> 3;
  const int hh0 = (t & 7) * 8;

  h8v f8 = *(const h8v*)&G[((size_t)(     b) << 18) + k8];
  h8v i8_ = *(const h8v*)&G[((size_t)( 8 + b) << 18) + k8];
  h8v o8 = *(const h8v*)&G[((size_t)(16 + b) << 18) + k8];
  h8v c8 = *(const h8v*)&G[((size_t)(24 + b) << 18) + k8];
  float4 s0 = *(const float4*)&struc[k8];
  float4 s1 = *(const float4*)&struc[k8 + 4];
  float sv[8] = {s0.x, s0.y, s0.z, s0.w, s1.x, s1.y, s1.z, s1.w};

  #pragma unroll
  for (int j = 0; j < 8; ++j) {
    float c = bf2f(f8[j]) * sv[j] + bf2f(i8_[j]) * bf2f(c8[j]);
    float hv = bf2f(o8[j]) * ftanh(c);
    hx[(hh0 + j) * 40 + nloc] = (uint8_t)f2i8(hv * 127.0f);
  }
  __syncthreads();
  {
    int row = t >> 2, seg = t & 3;
    uint2 v = *(const uint2*)&hx[row * 40 + seg * 8];
    *(uint2*)&PB[(size_t)(b * 64 + row) * 4096 + n0 + seg * 8] = v;
  }
}

// ---------------- Merged setup (r15) ----------------
__global__ __launch_bounds__(256)
void setup_all(const float* __restrict__ adj, int8_t* __restrict__ adj_i8,
               const float* __restrict__ W1, const float* __restrict__ W2,
               const float* __restrict__ Wih, const float* __restrict__ Whh,
               const float* __restrict__ D1,
               u16* __restrict__ WTf, u16* __restrict__ WihB,
               u16* __restrict__ WhhB, u16* __restrict__ D1t,
               const float* __restrict__ struc, int8_t* __restrict__ PB,
               const float* __restrict__ X, int8_t* __restrict__ Xp)
{
  const int blk = blockIdx.x;
  const int t = threadIdx.x;
  if (blk < 16384) {                         // conv_adj_i8
    size_t i = ((size_t)blk * 256 + t) * 4;
    float4 v = *(const float4*)(adj + i);
    const float s = 127.0f * 2048.0f;
    char4 o;
    o.x = f2i8(v.x * s); o.y = f2i8(v.y * s); o.z = f2i8(v.z * s); o.w = f2i8(v.w * s);
    *(char4*)(adj_i8 + i) = o;
  } else if (blk < 16616) {                  // build_w
    int gid = (blk - 16384) * 256 + t;
    if (gid < 24576) {
      int f = gid >> 9;          // frag 0..47
      int q = gid & 511;
      int ct = f / 3, kc = f - ct * 3;
      int c = q >> 3, e = q & 7;
      int rA = c >> 2, g = c & 3;
      int row = ct * 16 + rA;            // gate col 0..255
      int ch = kc * 32 + g * 8 + e;      // k index 0..95
      float v = 0.0f;
      int rr = (ch < 64) ? (ch + 4) : (ch < 68 ? ch - 64 : -1);
      if (rr >= 0) v = (row < 192) ? W1[(size_t)rr * 192 + row] : W2[(size_t)rr * 64 + (row - 192)];
      WTf[gid] = f2bf(v);
    } else if (gid < 40960) {
      int q = gid - 24576; WihB[q] = f2bf(Wih[q]);
    } else if (gid < 57344) {
      int q = gid - 40960; WhhB[q] = f2bf(Whh[q]);
    } else if (gid < 59392) {
      int q = gid - 57344;
      int j = q >> 6, hh = q & 63;
      D1t[q] = f2bf(D1[(size_t)hh * 32 + j]);
    }
  } else if (blk < 24808) {                  // init_pb
    int gid = (blk - 16616) * 256 + t;
    int n = gid & 4095;
    int r = gid >> 12;
    int hh = r & 63;
    PB[(size_t)r * 4096 + n] = f2i8(struc[(size_t)n * 64 + hh] * 25.4f);
  } else {                                   // pack_xall
    int gid = (blk - 24808) * 256 + t;
    int n = gid & 4095;
    int col = gid >> 12;
    int ts = col >> 5, r = col & 31, b = r >> 2, f = r & 3;
    Xp[(size_t)col * 4096 + n] = f2i8(X[(((size_t)(b * 12 + ts)) * 4096 + n) * 4 + f] * 25.4f);
  }
}

// ---------------- Fused decoder r17: enc(11) folded into prologue ------------
#define DSTR 80
__global__ __launch_bounds__(512, 4)
void dec_fused(const u16* __restrict__ G, const float* __restrict__ struc,
               float* __restrict__ zout,
               const u16* __restrict__ WihB, const u16* __restrict__ WhhB,
               const float* __restrict__ bih, const float* __restrict__ bhh,
               const u16* __restrict__ D1t, const float* __restrict__ bd1,
               const float* __restrict__ D2, const float* __restrict__ bd2,
               float* __restrict__ recon)
{
  __shared__ u16 whl[256 * DSTR];
  __shared__ u16 hl[64 * DSTR];
  __shared__ u16 zl[64 * DSTR];
  const int t = threadIdx.x;
  const int l = t & 63;
  const int w = t >> 6;          // 0..7
  const int wg = w >> 1;         // row group 0..3
  const int half = w & 1;        // gate-col half
  const int r0 = blockIdx.x * 64;
  const int rA = l & 15;
  const int kg = (l >> 4) * 8;

  // stage Whh
  for (int c = t; c < 2048; c += 512) {
    int j = c >> 3, k8 = (c & 7) * 8;
    *(uint4*)&whl[j * DSTR + k8] = *(const uint4*)&WhhB[j * 64 + k8];
  }

  // ---- enc(11) fold: compute z for this block's 64 rows from G ----
  {
    const int b = r0 >> 12;
    const size_t base = (size_t)(r0 & 4095) * 64 + t * 8;   // n*64+hh flat
    h8v f8 = *(const h8v*)&G[((size_t)(     b) << 18) + base];
    h8v i8_ = *(const h8v*)&G[((size_t)( 8 + b) << 18) + base];
    h8v o8 = *(const h8v*)&G[((size_t)(16 + b) << 18) + base];
    h8v c8 = *(const h8v*)&G[((size_t)(24 + b) << 18) + base];
    float4 s0 = *(const float4*)&struc[base];
    float4 s1 = *(const float4*)&struc[base + 4];
    float sv[8] = {s0.x, s0.y, s0.z, s0.w, s1.x, s1.y, s1.z, s1.w};
    float hv[8];
    #pragma unroll
    for (int j = 0; j < 8; ++j) {
      float c = bf2f(f8[j]) * sv[j] + bf2f(i8_[j]) * bf2f(c8[j]);
      hv[j] = bf2f(o8[j]) * ftanh(c);
    }
    float4 z0 = {hv[0], hv[1], hv[2], hv[3]};
    float4 z1 = {hv[4], hv[5], hv[6], hv[7]};
    *(float4*)&zout[((size_t)b << 18) + base] = z0;
    *(float4*)&zout[((size_t)b << 18) + base + 4] = z1;
    h8v zb;
    #pragma unroll
    for (int j = 0; j < 8; ++j) zb[j] = f2bf(hv[j]);
    *(h8v*)&zl[(t >> 3) * DSTR + (t & 7) * 8] = zb;
  }
  __syncthreads();   // zl + whl ready

  f4v xg[8];
  {
    s8v a0 = *(const s8v*)&zl[(wg * 16 + rA) * DSTR + kg];
    s8v a1 = *(const s8v*)&zl[(wg * 16 + rA) * DSTR + 32 + kg];
    #pragma unroll
    for (int j = 0; j < 8; ++j) {
      int nt = (j >> 1) * 4 + half * 2 + (j & 1);
      s8v b0 = *(const s8v*)&WihB[(nt * 16 + rA) * 64 + kg];
      s8v b1 = *(const s8v*)&WihB[(nt * 16 + rA) * 64 + 32 + kg];
      f4v a = (f4v)0.0f;
      a = __builtin_amdgcn_mfma_f32_16x16x32_bf16(a0, b0, a, 0, 0, 0);
      a = __builtin_amdgcn_mfma_f32_16x16x32_bf16(a1, b1, a, 0, 0, 0);
      float bb = bih[nt * 16 + rA] + bhh[nt * 16 + rA];
      #pragma unroll
      for (int r = 0; r < 4; ++r) xg[j][r] = a[r] + bb;
    }
  }
  s8v d1f[4];
  #pragma unroll
  for (int nt2 = 0; nt2 < 2; ++nt2)
    #pragma unroll
    for (int kc = 0; kc < 2; ++kc)
      d1f[nt2 * 2 + kc] = *(const s8v*)&D1t[(nt2 * 16 + rA) * 64 + kc * 32 + kg];
  const float bd1x = bd1[rA], bd1y = bd1[16 + rA];
  const float d2x = D2[rA], d2y = D2[16 + rA];
  const float bd2v = bd2[0];

  float cst[8];
  #pragma unroll
  for (int q = 0; q < 8; ++q) cst[q] = 0.0f;
  s8v ha0 = (s8v)0, ha1 = (s8v)0;

  for (int s = 0; s < 12; ++s) {
    f4v acc[8];
    #pragma unroll
    for (int j = 0; j < 8; ++j) acc[j] = xg[j];
    if (s > 0) {
      #pragma unroll
      for (int j = 0; j < 8; ++j) {
        int nt = (j >> 1) * 4 + half * 2 + (j & 1);
        s8v b0 = *(const s8v*)&whl[(nt * 16 + rA) * DSTR + kg];
        s8v b1 = *(const s8v*)&whl[(nt * 16 + rA) * DSTR + 32 + kg];
        acc[j] = __builtin_amdgcn_mfma_f32_16x16x32_bf16(ha0, b0, acc[j], 0, 0, 0);
        acc[j] = __builtin_amdgcn_mfma_f32_16x16x32_bf16(ha1, b1, acc[j], 0, 0, 0);
      }
    }
    __syncthreads();
    #pragma unroll
    for (int ql = 0; ql < 2; ++ql) {
      int q = half * 2 + ql;
      #pragma unroll
      for (int r = 0; r < 4; ++r) {
        float i_ = fsig (acc[0 + ql][r]);
        float f_ = fsig (acc[2 + ql][r]);
        float g_ = ftanh(acc[4 + ql][r]);
        float o_ = fsig (acc[6 + ql][r]);
        float cc = f_ * cst[ql * 4 + r] + i_ * g_;
        cst[ql * 4 + r] = cc;
        float hv = o_ * ftanh(cc);
        hl[(wg * 16 + (l >> 4) * 4 + r) * DSTR + q * 16 + rA] = f2bf(hv);
      }
    }
    __syncthreads();
    ha0 = *(const s8v*)&hl[(wg * 16 + rA) * DSTR + kg];
    ha1 = *(const s8v*)&hl[(wg * 16 + rA) * DSTR + 32 + kg];
    if (half == 0) {
      f4v m0 = (f4v)0.0f, m1 = (f4v)0.0f;
      m0 = __builtin_amdgcn_mfma_f32_16x16x32_bf16(ha0, d1f[0], m0, 0, 0, 0);
      m0 = __builtin_amdgcn_mfma_f32_16x16x32_bf16(ha1, d1f[1], m0, 0, 0, 0);
      m1 = __builtin_amdgcn_mfma_f32_16x16x32_bf16(ha0, d1f[2], m1, 0, 0, 0);
      m1 = __builtin_amdgcn_mfma_f32_16x16x32_bf16(ha1, d1f[3], m1, 0, 0, 0);
      f4v p;
      #pragma unroll
      for (int r = 0; r < 4; ++r)
        p[r] = fmaxf(m0[r] + bd1x, 0.0f) * d2x + fmaxf(m1[r] + bd1y, 0.0f) * d2y;
      #pragma unroll
      for (int mask = 1; mask < 16; mask <<= 1)
        #pragma unroll
        for (int r = 0; r < 4; ++r) p[r] += __shfl_xor(p[r], mask);
      if (rA < 4)
        recon[(size_t)(r0 + wg * 16 + (l >> 4) * 4 + rA) * 12 + s] = p[rA] + bd2v;
    }
  }
}

extern "C" void kernel_launch(void* const* d_in, const int* in_sizes, int n_in,
                              void* d_out, int out_size, void* d_ws, size_t ws_size,
                              hipStream_t stream)
{
  (void)in_sizes; (void)n_in; (void)out_size; (void)ws_size;
  const float* X     = (const float*)d_in[0];
  const float* adj   = (const float*)d_in[1];
  const float* struc = (const float*)d_in[2];
  const float* W1    = (const float*)d_in[3];
  const float* b1    = (const float*)d_in[4];
  const float* W2    = (const float*)d_in[5];
  const float* b2    = (const float*)d_in[6];
  const float* Wih   = (const float*)d_in[7];
  const float* Whh   = (const float*)d_in[8];
  const float* bih   = (const float*)d_in[9];
  const float* bhh   = (const float*)d_in[10];
  const float* D1    = (const float*)d_in[11];
  const float* bd1   = (const float*)d_in[12];
  const float* D2    = (const float*)d_in[13];
  const float* bd2   = (const float*)d_in[14];

  char* ws = (char*)d_ws;
  size_t off = 0;
  auto alloc = [&](size_t bytes){ void* p = ws + off; off += (bytes + 255) & ~(size_t)255; return p; };
  int8_t* adj_i8 = (int8_t*)alloc(4096ull * 4096);       // 16.75 MB
  int8_t* PB     = (int8_t*)alloc(512ull * 4096);        // h cols i8 [b*64+hh][n]
  int8_t* Xp     = (int8_t*)alloc(384ull * 4096);        // x cols i8 (scale 25.4)
  u16*   Cpart  = (u16*)  alloc(4ull * 4096 * 512 * 2);  // split-K slices (H)
  u16*   CpartX = (u16*)  alloc(4ull * 4096 * 384 * 2);  // split-K slices (X)
  u16*   G      = (u16*)  alloc(4ull * 8 * 262144 * 2);  // permuted gates
  u16*   WTf    = (u16*)  alloc(256ull * 96 * 2);        // fragment-ordered weights
  u16*   WihB   = (u16*)  alloc(256ull * 64 * 2);
  u16*   WhhB   = (u16*)  alloc(256ull * 64 * 2);
  u16*   D1t    = (u16*)  alloc(32ull * 64 * 2);

  float* zout  = (float*)d_out;                   // [B,N,H]
  float* recon = (float*)d_out + 2097152;         // [B*N, S] flat

  // dequant scales: adj lsb = 1/(127*2048); struc/X lsb = 1/25.4; h lsb = 1/127
  const float cs5 = (float)(2.0 / 4096.0 * 5.0 / (127.0 * 127.0));  // adj x (struc/X)
  const float cs1 = (float)(2.0 / 4096.0 * 1.0 / (127.0 * 127.0));  // adj x h

  setup_all<<<30952, 256, 0, stream>>>(adj, adj_i8, W1, W2, Wih, Whh, D1,
                                       WTf, WihB, WhhB, D1t, struc, PB, X, Xp);
  // combined: adj@X (by<3) + first adj@PB (by>=3), both at scale cs5
  gemm_s1_comb<<<dim3(32, 7, 4), 256, 0, stream>>>(adj_i8, Xp, PB, CpartX, Cpart,
                                                   1024, cs5);

  for (int t = 0; t < 12; ++t) {
    if (t > 0)
      gemm_s1_i8<<<dim3(32, 4, 4), 256, 0, stream>>>(adj_i8, PB, Cpart, 512, 1024, cs1);
    gemm_s2<<<512, 256, 0, stream>>>(Cpart, CpartX, WTf, b1, b2, G, t);
    if (t < 11)
      enc_update<<<1024, 256, 0, stream>>>(G, struc, PB);
  }

  dec_fused<<<512, 512, 0, stream>>>(G, struc, zout, WihB, WhhB, bih, bhh,
                                     D1t, bd1, D2, bd2, recon);
}

// Round 12
// 548.040 us; speedup vs baseline: 1.0215x; 1.0039x over previous
//
#include <hip/hip_runtime.h>
#include <cstdint>
#include <cstddef>

// B=8, S=12, N=4096, F=4, H=64
// r21 = r20 base (550us) with two traffic/LDS trims:
//  - struc converted ONCE to bf16 (sbf) in setup; enc_update (x11) and the
//    dec prologue read sbf (16B/thread instead of 32B). Saves ~50MB of fp32
//    re-reads across the encoder. Error: bf16 c0 adds <=0.4% on f*c0 term;
//    absmax budget 0.0146 >> expected ~0.008.
//  - dec_fused: zl aliased onto hl (zl is dead after xg; the s=0 in-loop
//    barrier orders all zl reads before the first hl write). LDS 61.4->51.2KB.
// Structural ledger (r16-r20): s1 at config optimum (all neighbors measured
// worse/null; i8 = precision floor); boundaries = cross-XCD floor (grid-sync
// 24x worse); s2+enc fusion impossible (flat-split permutation); dec grid-
// limited. This round trims the last measured-positive traffic slack.

typedef unsigned short u16;
typedef short s8v __attribute__((ext_vector_type(8)));     // 8 x bf16 bits
typedef unsigned short h8v __attribute__((ext_vector_type(8))); // 8 x u16
typedef float f4v __attribute__((ext_vector_type(4)));     // fp32 MFMA acc
typedef int   i4v __attribute__((ext_vector_type(4)));     // i8 MFMA operands/acc

__device__ __forceinline__ u16 f2bf(float x){
  union { float f; uint32_t u; } v; v.f = x;
  uint32_t r = v.u + 0x7FFFu + ((v.u >> 16) & 1u);   // RNE
  return (u16)(r >> 16);
}
__device__ __forceinline__ float bf2f(u16 x){
  union { uint32_t u; float f; } v; v.u = ((uint32_t)x) << 16; return v.f;
}
__device__ __forceinline__ float frcp(float x){ return __builtin_amdgcn_rcpf(x); }
__device__ __forceinline__ float fsig(float x){ return frcp(1.0f + __expf(-x)); }
__device__ __forceinline__ float ftanh(float x){ return 1.0f - 2.0f * frcp(1.0f + __expf(2.0f * x)); }
__device__ __forceinline__ int8_t f2i8(float x){
  int v = (int)rintf(x);
  v = v > 127 ? 127 : (v < -127 ? -127 : v);
  return (int8_t)v;
}

typedef const __attribute__((address_space(1))) unsigned int* gp_t;
typedef __attribute__((address_space(3))) unsigned int* lp_t;
__device__ __forceinline__ void glds16(const void* g, void* l){
  __builtin_amdgcn_global_load_lds((gp_t)g, (lp_t)l, 16, 0, 0);
}

// ---------------- Stage-1 INT8 core (r15): 128x128 tile, BK=128, dbuf --------
__device__ __forceinline__ void s1_core(int8_t* As, int8_t* Bs,
    const int8_t* __restrict__ A, const int8_t* __restrict__ Bt,
    u16* __restrict__ Cs, int Ncols, int ksl, float cscale,
    int mb, int nb, int k0)
{
  const int t  = threadIdx.x;
  const int l  = t & 63;
  const int w  = t >> 6;
  const int wm = (w >> 1) * 64;
  const int wc = (w & 1) * 64;

  i4v acc[4][4];
  #pragma unroll
  for (int i = 0; i < 4; ++i)
    #pragma unroll
    for (int j = 0; j < 4; ++j) acc[i][j] = (i4v)0;

  const int srow = t >> 3;
  const int gsw  = ((t & 7) ^ (srow & 7)) * 16;
  const int8_t* ab = A  + (size_t)(mb + srow) * 4096 + k0 + gsw;
  const int8_t* bb = Bt + (size_t)(nb + srow) * 4096 + k0 + gsw;

  const int rA = l & 15;
  const int lsw = l & 7;

  #pragma unroll
  for (int j = 0; j < 4; ++j) {
    glds16(ab + (size_t)(32 * j) * 4096, As + j * 4096 + t * 16);
    glds16(bb + (size_t)(32 * j) * 4096, Bs + j * 4096 + t * 16);
  }

  for (int kk = 0; kk < ksl; kk += 128) {
    const int cur = (kk >> 7) & 1;
    __syncthreads();
    if (kk + 128 < ksl) {
      const int nxt = cur ^ 1;
      #pragma unroll
      for (int j = 0; j < 4; ++j) {
        glds16(ab + (size_t)(32 * j) * 4096 + kk + 128, As + nxt * 16384 + j * 4096 + t * 16);
        glds16(bb + (size_t)(32 * j) * 4096 + kk + 128, Bs + nxt * 16384 + j * 4096 + t * 16);
      }
    }
    const int bofs = cur * 16384;
    #pragma unroll
    for (int sub = 0; sub < 2; ++sub) {
      const int kpos = ((sub * 4 + (l >> 4)) ^ lsw) * 16;
      i4v af[4], bf[4];
      #pragma unroll
      for (int mt = 0; mt < 4; ++mt)
        af[mt] = *(const i4v*)&As[bofs + (wm + mt * 16 + rA) * 128 + kpos];
      #pragma unroll
      for (int nt = 0; nt < 4; ++nt)
        bf[nt] = *(const i4v*)&Bs[bofs + (wc + nt * 16 + rA) * 128 + kpos];
      #pragma unroll
      for (int mt = 0; mt < 4; ++mt)
        #pragma unroll
        for (int nt = 0; nt < 4; ++nt)
          acc[mt][nt] = __builtin_amdgcn_mfma_i32_16x16x64_i8(af[mt], bf[nt], acc[mt][nt], 0, 0, 0);
    }
  }

  const int colo = l & 15;
  const int rowo = (l >> 4) * 4;
  #pragma unroll
  for (int mt = 0; mt < 4; ++mt)
    #pragma unroll
    for (int nt = 0; nt < 4; ++nt)
      #pragma unroll
      for (int r = 0; r < 4; ++r) {
        int gr = mb + wm + mt * 16 + rowo + r;
        int gc = nb + wc + nt * 16 + colo;
        Cs[(size_t)gr * Ncols + gc] = f2bf((float)acc[mt][nt][r] * cscale);
      }
}

__global__ __launch_bounds__(256)
void gemm_s1_i8(const int8_t* __restrict__ A, const int8_t* __restrict__ Bt,
                u16* __restrict__ Cpart, int Ncols, int ksl, float cscale)
{
  __shared__ int8_t As[2 * 128 * 128];
  __shared__ int8_t Bs[2 * 128 * 128];
  s1_core(As, Bs, A, Bt, Cpart + (size_t)blockIdx.z * 4096 * Ncols,
          Ncols, ksl, cscale, blockIdx.x * 128, blockIdx.y * 128,
          blockIdx.z * ksl);
}

// combined: by<3 -> X-part (Ncols 384), by>=3 -> PB-part (Ncols 512)
__global__ __launch_bounds__(256)
void gemm_s1_comb(const int8_t* __restrict__ A, const int8_t* __restrict__ Xp,
                  const int8_t* __restrict__ PB,
                  u16* __restrict__ CpX, u16* __restrict__ CpH,
                  int ksl, float cs)
{
  __shared__ int8_t As[2 * 128 * 128];
  __shared__ int8_t Bs[2 * 128 * 128];
  const int by = blockIdx.y;
  if (by < 3)
    s1_core(As, Bs, A, Xp, CpX + (size_t)blockIdx.z * 4096 * 384,
            384, ksl, cs, blockIdx.x * 128, by * 128, blockIdx.z * ksl);
  else
    s1_core(As, Bs, A, PB, CpH + (size_t)blockIdx.z * 4096 * 512,
            512, ksl, cs, blockIdx.x * 128, (by - 3) * 128, blockIdx.z * ksl);
}

// ---------- Stage-2 v4: As (4-slice AH sum | folded AX reduction | pad) in
// LDS; B-frags from fragment-ordered WTf (global, L1/L2-hot). Permuted G store.
__global__ __launch_bounds__(256)
void gemm_s2(const u16* __restrict__ AH, const u16* __restrict__ CpX,
             const u16* __restrict__ WTf, const float* __restrict__ b1v,
             const float* __restrict__ b2v, u16* __restrict__ G, int tstep)
{
  __shared__ u16 As[64 * 104];
  const int t = threadIdx.x;
  const int l = t & 63, w = t >> 6;
  const int wm = (w >> 1) * 32, wc0 = (w & 1) * 32;
  const int mb = blockIdx.x * 64;
  const size_t SL = 32768ull * 64;
  const size_t SLX = 4096ull * 384;

  #pragma unroll
  for (int pass = 0; pass < 2; ++pass) {
    int idx = t + pass * 256;
    int row = idx >> 3, oct = idx & 7;
    size_t base = (size_t)(mb + row) * 64 + oct * 8;
    float s[8] = {0,0,0,0,0,0,0,0};
    #pragma unroll
    for (int z = 0; z < 4; ++z) {
      uint4 v = *(const uint4*)(AH + z * SL + base);
      uint32_t wd[4] = {v.x, v.y, v.z, v.w};
      #pragma unroll
      for (int q = 0; q < 4; ++q) {
        union { uint32_t u; float f; } lo, hi;
        lo.u = wd[q] << 16; hi.u = wd[q] & 0xFFFF0000u;
        s[2*q] += lo.f; s[2*q+1] += hi.f;
      }
    }
    uint4 o; uint32_t* ow = (uint32_t*)&o;
    #pragma unroll
    for (int q = 0; q < 4; ++q)
      ow[q] = (uint32_t)f2bf(s[2*q]) | ((uint32_t)f2bf(s[2*q+1]) << 16);
    *(uint4*)&As[row * 104 + oct * 8] = o;
  }
  // x-cols (k 64..95): folded reduceN — sum 4 CpartX slices, f2bf in place.
  {
    int row = t >> 2, q = t & 3;
    uint4 o = {0, 0, 0, 0};
    if (q == 0) {
      int r = mb + row, n = r >> 3, b = r & 7;
      size_t base = (size_t)n * 384 + tstep * 32 + b * 4;
      float s[4] = {0, 0, 0, 0};
      #pragma unroll
      for (int z = 0; z < 4; ++z) {
        uint2 v = *(const uint2*)(CpX + z * SLX + base);
        uint32_t wd[2] = {v.x, v.y};
        #pragma unroll
        for (int qq = 0; qq < 2; ++qq) {
          union { uint32_t u; float f; } lo, hi;
          lo.u = wd[qq] << 16; hi.u = wd[qq] & 0xFFFF0000u;
          s[2*qq] += lo.f; s[2*qq+1] += hi.f;
        }
      }
      uint32_t* ow = (uint32_t*)&o;
      ow[0] = (uint32_t)f2bf(s[0]) | ((uint32_t)f2bf(s[1]) << 16);
      ow[1] = (uint32_t)f2bf(s[2]) | ((uint32_t)f2bf(s[3]) << 16);
    }
    *(uint4*)&As[row * 104 + 64 + q * 8] = o;
  }
  __syncthreads();

  const int rA = l & 15, kg = (l >> 4) * 8;
  s8v af[3][2];
  #pragma unroll
  for (int kc = 0; kc < 3; ++kc)
    #pragma unroll
    for (int mt = 0; mt < 2; ++mt)
      af[kc][mt] = *(const s8v*)&As[(wm + mt * 16 + rA) * 104 + kc * 32 + kg];

  const int lchunk = ((l & 15) * 4 + (l >> 4)) * 8;   // lane offset in frag (u16)
  const int colo = l & 15, rowo = (l >> 4) * 4;
  #pragma unroll
  for (int nb4 = 0; nb4 < 4; ++nb4) {
    const int wc = nb4 * 64 + wc0;
    f4v acc[2][2];
    #pragma unroll
    for (int i = 0; i < 2; ++i)
      #pragma unroll
      for (int j = 0; j < 2; ++j) acc[i][j] = (f4v)0.0f;
    #pragma unroll
    for (int kc = 0; kc < 3; ++kc) {
      s8v bf[2];
      #pragma unroll
      for (int nt = 0; nt < 2; ++nt) {
        int ct = nb4 * 4 + (w & 1) * 2 + nt;
        bf[nt] = *(const s8v*)&WTf[(ct * 3 + kc) * 512 + lchunk];
      }
      #pragma unroll
      for (int mt = 0; mt < 2; ++mt)
        #pragma unroll
        for (int nt = 0; nt < 2; ++nt)
          acc[mt][nt] = __builtin_amdgcn_mfma_f32_16x16x32_bf16(af[kc][mt], bf[nt], acc[mt][nt], 0, 0, 0);
    }
    #pragma unroll
    for (int mt = 0; mt < 2; ++mt)
      #pragma unroll
      for (int nt = 0; nt < 2; ++nt) {
        int gc = wc + nt * 16 + colo;
        float bb = (gc < 192) ? b1v[gc] : b2v[gc - 192];
        #pragma unroll
        for (int r = 0; r < 4; ++r) {
          int gr = mb + wm + mt * 16 + rowo + r;
          int np = gr >> 3, b = gr & 7;
          float v = acc[mt][nt][r] + bb;
          size_t addr;
          u16 val;
          if (gc < 192) {
            int p = np * 192 + gc;
            int role = p >> 18;
            int k = p & 262143;
            addr = ((size_t)(role * 8 + b) << 18) + k;
            val = f2bf(fsig(v));
          } else {
            int k = np * 64 + (gc - 192);
            addr = ((size_t)(24 + b) << 18) + k;
            val = f2bf(ftanh(v));
          }
          G[addr] = val;
        }
      }
  }
}

// enc_update (t = 0..10 only): h update + PB repack. struc as bf16 (sbf).
__global__ __launch_bounds__(256)
void enc_update(const u16* __restrict__ G, const u16* __restrict__ sbf,
                int8_t* __restrict__ PB)
{
  __shared__ uint8_t hx[64 * 40];
  const int t = threadIdx.x;
  const int b = blockIdx.x >> 7;
  const int n0 = (blockIdx.x & 127) * 32;
  const int k8 = n0 * 64 + t * 8;
  const int nloc = t >> 3;
  const int hh0 = (t & 7) * 8;

  h8v f8 = *(const h8v*)&G[((size_t)(     b) << 18) + k8];
  h8v i8_ = *(const h8v*)&G[((size_t)( 8 + b) << 18) + k8];
  h8v o8 = *(const h8v*)&G[((size_t)(16 + b) << 18) + k8];
  h8v c8 = *(const h8v*)&G[((size_t)(24 + b) << 18) + k8];
  h8v sv8 = *(const h8v*)&sbf[k8];

  #pragma unroll
  for (int j = 0; j < 8; ++j) {
    float c = bf2f(f8[j]) * bf2f(sv8[j]) + bf2f(i8_[j]) * bf2f(c8[j]);
    float hv = bf2f(o8[j]) * ftanh(c);
    hx[(hh0 + j) * 40 + nloc] = (uint8_t)f2i8(hv * 127.0f);
  }
  __syncthreads();
  {
    int row = t >> 2, seg = t & 3;
    uint2 v = *(const uint2*)&hx[row * 40 + seg * 8];
    *(uint2*)&PB[(size_t)(b * 64 + row) * 4096 + n0 + seg * 8] = v;
  }
}

// ---------------- Merged setup (r15 + sbf conversion) ----------------
__global__ __launch_bounds__(256)
void setup_all(const float* __restrict__ adj, int8_t* __restrict__ adj_i8,
               const float* __restrict__ W1, const float* __restrict__ W2,
               const float* __restrict__ Wih, const float* __restrict__ Whh,
               const float* __restrict__ D1,
               u16* __restrict__ WTf, u16* __restrict__ WihB,
               u16* __restrict__ WhhB, u16* __restrict__ D1t,
               const float* __restrict__ struc, int8_t* __restrict__ PB,
               const float* __restrict__ X, int8_t* __restrict__ Xp,
               u16* __restrict__ sbf)
{
  const int blk = blockIdx.x;
  const int t = threadIdx.x;
  if (blk < 16384) {                         // conv_adj_i8
    size_t i = ((size_t)blk * 256 + t) * 4;
    float4 v = *(const float4*)(adj + i);
    const float s = 127.0f * 2048.0f;
    char4 o;
    o.x = f2i8(v.x * s); o.y = f2i8(v.y * s); o.z = f2i8(v.z * s); o.w = f2i8(v.w * s);
    *(char4*)(adj_i8 + i) = o;
  } else if (blk < 16616) {                  // build_w
    int gid = (blk - 16384) * 256 + t;
    if (gid < 24576) {
      int f = gid >> 9;          // frag 0..47
      int q = gid & 511;
      int ct = f / 3, kc = f - ct * 3;
      int c = q >> 3, e = q & 7;
      int rA = c >> 2, g = c & 3;
      int row = ct * 16 + rA;            // gate col 0..255
      int ch = kc * 32 + g * 8 + e;      // k index 0..95
      float v = 0.0f;
      int rr = (ch < 64) ? (ch + 4) : (ch < 68 ? ch - 64 : -1);
      if (rr >= 0) v = (row < 192) ? W1[(size_t)rr * 192 + row] : W2[(size_t)rr * 64 + (row - 192)];
      WTf[gid] = f2bf(v);
    } else if (gid < 40960) {
      int q = gid - 24576; WihB[q] = f2bf(Wih[q]);
    } else if (gid < 57344) {
      int q = gid - 40960; WhhB[q] = f2bf(Whh[q]);
    } else if (gid < 59392) {
      int q = gid - 57344;
      int j = q >> 6, hh = q & 63;
      D1t[q] = f2bf(D1[(size_t)hh * 32 + j]);
    }
  } else if (blk < 24808) {                  // init_pb
    int gid = (blk - 16616) * 256 + t;
    int n = gid & 4095;
    int r = gid >> 12;
    int hh = r & 63;
    PB[(size_t)r * 4096 + n] = f2i8(struc[(size_t)n * 64 + hh] * 25.4f);
  } else if (blk < 30952) {                  // pack_xall
    int gid = (blk - 24808) * 256 + t;
    int n = gid & 4095;
    int col = gid >> 12;
    int ts = col >> 5, r = col & 31, b = r >> 2, f = r & 3;
    Xp[(size_t)col * 4096 + n] = f2i8(X[(((size_t)(b * 12 + ts)) * 4096 + n) * 4 + f] * 25.4f);
  } else {                                   // struc -> bf16 (262144 elems)
    size_t i = ((size_t)(blk - 30952) * 256 + t) * 8;
    float4 a = *(const float4*)(struc + i);
    float4 b = *(const float4*)(struc + i + 4);
    h8v o;
    o[0] = f2bf(a.x); o[1] = f2bf(a.y); o[2] = f2bf(a.z); o[3] = f2bf(a.w);
    o[4] = f2bf(b.x); o[5] = f2bf(b.y); o[6] = f2bf(b.z); o[7] = f2bf(b.w);
    *(h8v*)&sbf[i] = o;
  }
}

// ---------------- Fused decoder r21: enc(11) fold + zl aliased onto hl -------
// Safety of alias: all zl(hl) reads happen in the xg computation, which
// completes before the s=0 iteration's __syncthreads(); hl writes occur only
// after that barrier.
#define DSTR 80
__global__ __launch_bounds__(512, 4)
void dec_fused(const u16* __restrict__ G, const u16* __restrict__ sbf,
               float* __restrict__ zout,
               const u16* __restrict__ WihB, const u16* __restrict__ WhhB,
               const float* __restrict__ bih, const float* __restrict__ bhh,
               const u16* __restrict__ D1t, const float* __restrict__ bd1,
               const float* __restrict__ D2, const float* __restrict__ bd2,
               float* __restrict__ recon)
{
  __shared__ u16 whl[256 * DSTR];
  __shared__ u16 hl[64 * DSTR];          // doubles as z staging (prologue)
  const int t = threadIdx.x;
  const int l = t & 63;
  const int w = t >> 6;          // 0..7
  const int wg = w >> 1;         // row group 0..3
  const int half = w & 1;        // gate-col half
  const int r0 = blockIdx.x * 64;
  const int rA = l & 15;
  const int kg = (l >> 4) * 8;

  // stage Whh
  for (int c = t; c < 2048; c += 512) {
    int j = c >> 3, k8 = (c & 7) * 8;
    *(uint4*)&whl[j * DSTR + k8] = *(const uint4*)&WhhB[j * 64 + k8];
  }

  // ---- enc(11) fold: compute z for this block's 64 rows from G ----
  {
    const int b = r0 >> 12;
    const size_t base = (size_t)(r0 & 4095) * 64 + t * 8;   // n*64+hh flat
    h8v f8 = *(const h8v*)&G[((size_t)(     b) << 18) + base];
    h8v i8_ = *(const h8v*)&G[((size_t)( 8 + b) << 18) + base];
    h8v o8 = *(const h8v*)&G[((size_t)(16 + b) << 18) + base];
    h8v c8 = *(const h8v*)&G[((size_t)(24 + b) << 18) + base];
    h8v sv8 = *(const h8v*)&sbf[base];
    float hv[8];
    #pragma unroll
    for (int j = 0; j < 8; ++j) {
      float c = bf2f(f8[j]) * bf2f(sv8[j]) + bf2f(i8_[j]) * bf2f(c8[j]);
      hv[j] = bf2f(o8[j]) * ftanh(c);
    }
    float4 z0 = {hv[0], hv[1], hv[2], hv[3]};
    float4 z1 = {hv[4], hv[5], hv[6], hv[7]};
    *(float4*)&zout[((size_t)b << 18) + base] = z0;
    *(float4*)&zout[((size_t)b << 18) + base + 4] = z1;
    h8v zb;
    #pragma unroll
    for (int j = 0; j < 8; ++j) zb[j] = f2bf(hv[j]);
    *(h8v*)&hl[(t >> 3) * DSTR + (t & 7) * 8] = zb;   // z staged in hl
  }
  __syncthreads();   // z(hl) + whl ready

  f4v xg[8];
  {
    s8v a0 = *(const s8v*)&hl[(wg * 16 + rA) * DSTR + kg];
    s8v a1 = *(const s8v*)&hl[(wg * 16 + rA) * DSTR + 32 + kg];
    #pragma unroll
    for (int j = 0; j < 8; ++j) {
      int nt = (j >> 1) * 4 + half * 2 + (j & 1);
      s8v b0 = *(const s8v*)&WihB[(nt * 16 + rA) * 64 + kg];
      s8v b1 = *(const s8v*)&WihB[(nt * 16 + rA) * 64 + 32 + kg];
      f4v a = (f4v)0.0f;
      a = __builtin_amdgcn_mfma_f32_16x16x32_bf16(a0, b0, a, 0, 0, 0);
      a = __builtin_amdgcn_mfma_f32_16x16x32_bf16(a1, b1, a, 0, 0, 0);
      float bb = bih[nt * 16 + rA] + bhh[nt * 16 + rA];
      #pragma unroll
      for (int r = 0; r < 4; ++r) xg[j][r] = a[r] + bb;
    }
  }
  s8v d1f[4];
  #pragma unroll
  for (int nt2 = 0; nt2 < 2; ++nt2)
    #pragma unroll
    for (int kc = 0; kc < 2; ++kc)
      d1f[nt2 * 2 + kc] = *(const s8v*)&D1t[(nt2 * 16 + rA) * 64 + kc * 32 + kg];
  const float bd1x = bd1[rA], bd1y = bd1[16 + rA];
  const float d2x = D2[rA], d2y = D2[16 + rA];
  const float bd2v = bd2[0];

  float cst[8];
  #pragma unroll
  for (int q = 0; q < 8; ++q) cst[q] = 0.0f;
  s8v ha0 = (s8v)0, ha1 = (s8v)0;

  for (int s = 0; s < 12; ++s) {
    f4v acc[8];
    #pragma unroll
    for (int j = 0; j < 8; ++j) acc[j] = xg[j];
    if (s > 0) {
      #pragma unroll
      for (int j = 0; j < 8; ++j) {
        int nt = (j >> 1) * 4 + half * 2 + (j & 1);
        s8v b0 = *(const s8v*)&whl[(nt * 16 + rA) * DSTR + kg];
        s8v b1 = *(const s8v*)&whl[(nt * 16 + rA) * DSTR + 32 + kg];
        acc[j] = __builtin_amdgcn_mfma_f32_16x16x32_bf16(ha0, b0, acc[j], 0, 0, 0);
        acc[j] = __builtin_amdgcn_mfma_f32_16x16x32_bf16(ha1, b1, acc[j], 0, 0, 0);
      }
    }
    __syncthreads();   // orders prior hl reads (z in s=0; ha in s>0) before writes
    #pragma unroll
    for (int ql = 0; ql < 2; ++ql) {
      int q = half * 2 + ql;
      #pragma unroll
      for (int r = 0; r < 4; ++r) {
        float i_ = fsig (acc[0 + ql][r]);
        float f_ = fsig (acc[2 + ql][r]);
        float g_ = ftanh(acc[4 + ql][r]);
        float o_ = fsig (acc[6 + ql][r]);
        float cc = f_ * cst[ql * 4 + r] + i_ * g_;
        cst[ql * 4 + r] = cc;
        float hv = o_ * ftanh(cc);
        hl[(wg * 16 + (l >> 4) * 4 + r) * DSTR + q * 16 + rA] = f2bf(hv);
      }
    }
    __syncthreads();
    ha0 = *(const s8v*)&hl[(wg * 16 + rA) * DSTR + kg];
    ha1 = *(const s8v*)&hl[(wg * 16 + rA) * DSTR + 32 + kg];
    if (half == 0) {
      f4v m0 = (f4v)0.0f, m1 = (f4v)0.0f;
      m0 = __builtin_amdgcn_mfma_f32_16x16x32_bf16(ha0, d1f[0], m0, 0, 0, 0);
      m0 = __builtin_amdgcn_mfma_f32_16x16x32_bf16(ha1, d1f[1], m0, 0, 0, 0);
      m1 = __builtin_amdgcn_mfma_f32_16x16x32_bf16(ha0, d1f[2], m1, 0, 0, 0);
      m1 = __builtin_amdgcn_mfma_f32_16x16x32_bf16(ha1, d1f[3], m1, 0, 0, 0);
      f4v p;
      #pragma unroll
      for (int r = 0; r < 4; ++r)
        p[r] = fmaxf(m0[r] + bd1x, 0.0f) * d2x + fmaxf(m1[r] + bd1y, 0.0f) * d2y;
      #pragma unroll
      for (int mask = 1; mask < 16; mask <<= 1)
        #pragma unroll
        for (int r = 0; r < 4; ++r) p[r] += __shfl_xor(p[r], mask);
      if (rA < 4)
        recon[(size_t)(r0 + wg * 16 + (l >> 4) * 4 + rA) * 12 + s] = p[rA] + bd2v;
    }
  }
}

extern "C" void kernel_launch(void* const* d_in, const int* in_sizes, int n_in,
                              void* d_out, int out_size, void* d_ws, size_t ws_size,
                              hipStream_t stream)
{
  (void)in_sizes; (void)n_in; (void)out_size; (void)ws_size;
  const float* X     = (const float*)d_in[0];
  const float* adj   = (const float*)d_in[1];
  const float* struc = (const float*)d_in[2];
  const float* W1    = (const float*)d_in[3];
  const float* b1    = (const float*)d_in[4];
  const float* W2    = (const float*)d_in[5];
  const float* b2    = (const float*)d_in[6];
  const float* Wih   = (const float*)d_in[7];
  const float* Whh   = (const float*)d_in[8];
  const float* bih   = (const float*)d_in[9];
  const float* bhh   = (const float*)d_in[10];
  const float* D1    = (const float*)d_in[11];
  const float* bd1   = (const float*)d_in[12];
  const float* D2    = (const float*)d_in[13];
  const float* bd2   = (const float*)d_in[14];

  char* ws = (char*)d_ws;
  size_t off = 0;
  auto alloc = [&](size_t bytes){ void* p = ws + off; off += (bytes + 255) & ~(size_t)255; return p; };
  int8_t* adj_i8 = (int8_t*)alloc(4096ull * 4096);       // 16.75 MB
  int8_t* PB     = (int8_t*)alloc(512ull * 4096);        // h cols i8 [b*64+hh][n]
  int8_t* Xp     = (int8_t*)alloc(384ull * 4096);        // x cols i8 (scale 25.4)
  u16*   Cpart  = (u16*)  alloc(4ull * 4096 * 512 * 2);  // split-K slices (H)
  u16*   CpartX = (u16*)  alloc(4ull * 4096 * 384 * 2);  // split-K slices (X)
  u16*   G      = (u16*)  alloc(4ull * 8 * 262144 * 2);  // permuted gates
  u16*   WTf    = (u16*)  alloc(256ull * 96 * 2);        // fragment-ordered weights
  u16*   WihB   = (u16*)  alloc(256ull * 64 * 2);
  u16*   WhhB   = (u16*)  alloc(256ull * 64 * 2);
  u16*   D1t    = (u16*)  alloc(32ull * 64 * 2);
  u16*   sbf    = (u16*)  alloc(262144ull * 2);          // struc as bf16

  float* zout  = (float*)d_out;                   // [B,N,H]
  float* recon = (float*)d_out + 2097152;         // [B*N, S] flat

  // dequant scales: adj lsb = 1/(127*2048); struc/X lsb = 1/25.4; h lsb = 1/127
  const float cs5 = (float)(2.0 / 4096.0 * 5.0 / (127.0 * 127.0));  // adj x (struc/X)
  const float cs1 = (float)(2.0 / 4096.0 * 1.0 / (127.0 * 127.0));  // adj x h

  setup_all<<<31080, 256, 0, stream>>>(adj, adj_i8, W1, W2, Wih, Whh, D1,
                                       WTf, WihB, WhhB, D1t, struc, PB, X, Xp,
                                       sbf);
  // combined: adj@X (by<3) + first adj@PB (by>=3), both at scale cs5
  gemm_s1_comb<<<dim3(32, 7, 4), 256, 0, stream>>>(adj_i8, Xp, PB, CpartX, Cpart,
                                                   1024, cs5);

  for (int t = 0; t < 12; ++t) {
    if (t > 0)
      gemm_s1_i8<<<dim3(32, 4, 4), 256, 0, stream>>>(adj_i8, PB, Cpart, 512, 1024, cs1);
    gemm_s2<<<512, 256, 0, stream>>>(Cpart, CpartX, WTf, b1, b2, G, t);
    if (t < 11)
      enc_update<<<1024, 256, 0, stream>>>(G, sbf, PB);
  }

  dec_fused<<<512, 512, 0, stream>>>(G, sbf, zout, WihB, WhhB, bih, bhh,
                                     D1t, bd1, D2, bd2, recon);
}